// Round 5
// baseline (124.915 us; speedup 1.0000x reference)
//
#include <hip/hip_runtime.h>

// Problem constants
#define HW_   36864      // 192*192
#define WI    192
#define HT    192
#define CIN   128
#define DK    256        // == D_V
#define NH    8
#define DKH   32         // channels per head
// TEMPER = 16 -> scale 1/16 = 0.0625

// Fused-kernel tile geometry
#define TW    16         // interior tile 16x4
#define TH    4
#define HWH   18         // halo 18x6 = 108 px
#define HHH   6
#define HPX   108
#define HPAD  112        // 7 MFMA n-tiles (tiles cover px 0..111; 108..111 garbage, never gathered)
#define VTS   36         // Vt row stride in shorts (72B: 18 dwords, gcd(18,32)=2 -> 2-way=free)

using short4_ = __attribute__((ext_vector_type(4))) short;
using short8  = __attribute__((ext_vector_type(8))) short;
using float4_ = __attribute__((ext_vector_type(4))) float;

static __device__ __forceinline__ float b2f(unsigned short u) {
    union { unsigned int i; float f; } x; x.i = ((unsigned int)u) << 16; return x.f;
}
static __device__ __forceinline__ unsigned short f2b(float f) {
    union { float f; unsigned int i; } x; x.f = f;
    unsigned int r = x.i + 0x7FFFu + ((x.i >> 16) & 1u);   // round-nearest-even
    return (unsigned short)(r >> 16);
}

// ---------------------------------------------------------------------------
// Kernel 1: weights fp32 -> bf16 wqkv[8][96][128], interleaved row layout
// per head (verified r1):
//   rows  0-15 : q[ 0:16]   rows 16-31 : k[ 0:16]   rows 32-47 : v[ 0:16]
//   rows 48-63 : q[16:32]   rows 64-79 : k[16:32]   rows 80-95 : v[16:32]
// (UNCHANGED)
// ---------------------------------------------------------------------------
__global__ __launch_bounds__(256) void convw_kernel(
    const float* __restrict__ wq,
    const float* __restrict__ wk,
    const float* __restrict__ wv,
    unsigned short* __restrict__ wqkv)
{
    int id = blockIdx.x * 256 + threadIdx.x;   // 98304 = 8*96*128
    int h   = id / 12288;
    int rem = id - h * 12288;
    int r   = rem >> 7;                        // 0..95
    int c   = rem & 127;
    int g   = r >> 4;                          // 0..5
    int gm  = g % 3;                           // 0=q 1=k 2=v
    int rr  = ((g >= 3) ? 16 : 0) + (r & 15);  // channel within head half
    const float* __restrict__ s = (gm == 0) ? wq : ((gm == 1) ? wk : wv);
    wqkv[id] = f2b(s[(h * 32 + rr) * 128 + c]);
}

// ---------------------------------------------------------------------------
// Kernel 2 (FUSED v2) — fixes r4's three measured pathologies:
//   r4 counters: 53us, Occupancy 17.5%, MfmaUtil 7.8%, 1.81M bank conflicts
//   -> latency-bound staging + conflicted gather + 2 blocks/CU.
// Fixes:
//   1. 16x4 interior / 18x6 halo tile: LDS 39.4KB -> 4 blocks/CU; grid
//      1152 (4.5/CU, 16 waves/CU of TLP).
//   2. Staging: all 256 threads; thread owns ONE halo px (address hoisted),
//      sweeps 64 channel planes with independent coalesced loads.
//   3. Vt stride 36 shorts (18 dwords, gcd 2 with 32 banks -> 2-way = free),
//      aligned b64 reads; gather = 64 px x 4 cg, all lanes active.
// Math is op-identical to the r4-passed kernel (A-fragments, MFMA pattern,
// score reduce, softmax order, f2b/b2f). n-tile 3 is computed by both wn
// waves (same wm -> same a, same bb -> bitwise-identical writes: benign).
// XCD swizzle: wg=(b&7)*144+(b>>3) (1152%8==0, bijective): each XCD gets
// 72 consecutive tiles x 2 head-groups -> 2.6MB x-band fits 4MB L2.
// ---------------------------------------------------------------------------
__global__ __launch_bounds__(256) void fusedattn2_kernel(
    const float* __restrict__ x,               // [128][HW] fp32
    const unsigned short* __restrict__ wqkv,   // [8][96][128] bf16 (interleaved)
    float* __restrict__ out)                   // [256][HW] fp32
{
    __shared__ __align__(16) unsigned short Bs[HPAD * 136]; // 30464 B halo px
    __shared__ __align__(16) unsigned short Vt[HPAD * VTS]; // 8064 B v (bf16)
    __shared__ float Sc[2][HPAD];                           // 896 B q.k partials

    const int b    = blockIdx.x;               // 1152 = 576 tiles * 2 hgroups
    const int wg   = (b & 7) * 144 + (b >> 3); // XCD swizzle
    const int hbase = (wg & 1) * 4;
    const int tile  = wg >> 1;                 // 0..575
    const int ty = tile / 12, tx = tile - ty * 12;   // 12 x 48 tile grid
    const int y0 = ty * TH, x0 = tx * TW;

    const int t    = threadIdx.x;
    const int lane = t & 63, wave = t >> 6;
    const int col  = lane & 15, quad = lane >> 4;
    const int wm   = wave >> 1, wn = wave & 1;

    // ---- prefetch head hbase A-fragments straight into registers ----
    short8 a[3][4];
    {
        const unsigned short* __restrict__ Ag = wqkv + hbase * 12288;
        #pragma unroll
        for (int mt = 0; mt < 3; ++mt)
            #pragma unroll
            for (int kt = 0; kt < 4; ++kt)
                a[mt][kt] = *(const short8*)&Ag[(wm * 48 + mt * 16 + col) * 128 + kt * 32 + quad * 8];
    }

    // ---- stage Bs cooperatively: thread -> one halo px, sweep 64 c-planes ----
    {
        const int p  = t & 127;                // constant per thread
        const int cb = t >> 7;                 // plane parity (0/1)
        if (p < HPX) {
            int hy = p / HWH, hx = p - hy * HWH;
            int gy = y0 - 1 + hy; gy = gy < 0 ? 0 : (gy > HT - 1 ? HT - 1 : gy);
            int gx = x0 - 1 + hx; gx = gx < 0 ? 0 : (gx > WI - 1 ? WI - 1 : gx);
            const float* __restrict__ xp = x + gy * WI + gx;
            unsigned short* __restrict__ bp = Bs + p * 136;
            #pragma unroll 8
            for (int i = 0; i < 64; ++i) {
                int c = cb + 2 * i;
                bp[c] = f2b(xp[(size_t)c * HW_]);
            }
        }
    }
    __syncthreads();                           // Bs ready

    for (int hh = 0; hh < 4; ++hh) {
        const int head = hbase + hh;

        // ---- MFMA: acc[mt][j], mt: 0=q 1=k 2=v chunk of this wm half ----
        float4_ acc[3][4];
        #pragma unroll
        for (int mt = 0; mt < 3; ++mt)
            #pragma unroll
            for (int j = 0; j < 4; ++j)
                acc[mt][j] = (float4_){0.f, 0.f, 0.f, 0.f};

        #pragma unroll
        for (int j = 0; j < 4; ++j) {
            const int p = (wn * 3 + j) * 16 + col;   // tiles 0-3 / 3-6 (3 dup, benign)
            short8 bb[4];
            #pragma unroll
            for (int kt = 0; kt < 4; ++kt)
                bb[kt] = *(const short8*)&Bs[p * 136 + kt * 32 + quad * 8];
            #pragma unroll
            for (int mt = 0; mt < 3; ++mt)
                #pragma unroll
                for (int kt = 0; kt < 4; ++kt)
                    acc[mt][j] = __builtin_amdgcn_mfma_f32_16x16x32_bf16(a[mt][kt], bb[kt], acc[mt][j], 0, 0, 0);
        }

        // ---- prefetch next head's A-fragments (a[] dead after MFMA) ----
        if (hh < 3) {
            const unsigned short* __restrict__ Ag = wqkv + (head + 1) * 12288;
            #pragma unroll
            for (int mt = 0; mt < 3; ++mt)
                #pragma unroll
                for (int kt = 0; kt < 4; ++kt)
                    a[mt][kt] = *(const short8*)&Ag[(wm * 48 + mt * 16 + col) * 128 + kt * 32 + quad * 8];
        }

        // ---- epilogue: scores partial + v (bf16) into LDS ----
        #pragma unroll
        for (int j = 0; j < 4; ++j) {
            const int p = (wn * 3 + j) * 16 + col;
            float s = 0.f;
            #pragma unroll
            for (int reg = 0; reg < 4; ++reg)
                s += acc[0][j][reg] * acc[1][j][reg];    // q.k partial (16 dk of wm)
            s += __shfl_xor(s, 16, 64);
            s += __shfl_xor(s, 32, 64);
            if (quad == 0) Sc[wm][p] = s;
            short4_ v0;
            #pragma unroll
            for (int reg = 0; reg < 4; ++reg)
                v0[reg] = (short)f2b(acc[2][j][reg]);
            *(short4_*)&Vt[p * VTS + wm * 16 + quad * 4] = v0;
        }
        __syncthreads();                       // Sc/Vt ready

        // ---- softmax + gather + direct out (op-identical verified math) ----
        {
            const int pxl = t >> 2;            // 0..63 interior px
            const int cg  = t & 3;             // 8-channel group
            const int ly  = pxl >> 4, lx = pxl & 15;
            const int y   = y0 + ly, xx = x0 + lx;

            float w[9];
            float m = -1e30f;
            #pragma unroll
            for (int r = 0; r < 9; ++r) {
                int dy = r / 3 - 1, dx = r % 3 - 1;
                int ny = y + dy, nx = xx + dx;
                bool inb = (ny >= 0) && (ny < HT) && (nx >= 0) && (nx < WI);
                int hp = (ly + 1 + dy) * HWH + lx + 1 + dx;
                float val = inb ? ((Sc[0][hp] + Sc[1][hp]) * 0.0625f) : 0.0f;
                w[r] = val;
                m = fmaxf(m, val);
            }
            float wsum = 0.f;
            #pragma unroll
            for (int r = 0; r < 9; ++r) {
                float e = __expf(w[r] - m);
                w[r] = e;
                wsum += e;
            }
            float inv = 1.0f / wsum;
            #pragma unroll
            for (int r = 0; r < 9; ++r) {
                int dy = r / 3 - 1, dx = r % 3 - 1;
                int ny = y + dy, nx = xx + dx;
                bool inb = (ny >= 0) && (ny < HT) && (nx >= 0) && (nx < WI);
                w[r] = inb ? (w[r] * inv) : 0.0f;
            }

            float o[8];
            #pragma unroll
            for (int j2 = 0; j2 < 8; ++j2) o[j2] = 0.f;
            #pragma unroll
            for (int r = 0; r < 9; ++r) {
                int dy = r / 3 - 1, dx = r % 3 - 1;
                int hp = (ly + 1 + dy) * HWH + lx + 1 + dx;
                // aligned b64 pair (stride-36 rows are 8B-aligned, 16B only even rows)
                short4_ va = *(const short4_*)&Vt[hp * VTS + cg * 8];
                short4_ vb = *(const short4_*)&Vt[hp * VTS + cg * 8 + 4];
                #pragma unroll
                for (int j2 = 0; j2 < 4; ++j2) {
                    o[j2]     = fmaf(w[r], b2f((unsigned short)va[j2]), o[j2]);
                    o[4 + j2] = fmaf(w[r], b2f((unsigned short)vb[j2]), o[4 + j2]);
                }
            }
            float* op = out + (size_t)(head * DKH + cg * 8) * HW_ + y * WI + xx;
            #pragma unroll
            for (int j2 = 0; j2 < 8; ++j2)
                op[(size_t)j2 * HW_] = o[j2];
        }
        __syncthreads();                       // gather done before next epilogue
    }
}

// ---------------------------------------------------------------------------
// Workspace layout:
//   [0, 196608)  wqkv : 8*96*128 bf16
// ---------------------------------------------------------------------------
extern "C" void kernel_launch(void* const* d_in, const int* in_sizes, int n_in,
                              void* d_out, int out_size, void* d_ws, size_t ws_size,
                              hipStream_t stream) {
    const float* x  = (const float*)d_in[0];
    const float* wq = (const float*)d_in[1];
    const float* wk = (const float*)d_in[2];
    const float* wv = (const float*)d_in[3];

    unsigned short* wqkv = (unsigned short*)d_ws;

    convw_kernel<<<384, 256, 0, stream>>>(wq, wk, wv, wqkv);
    fusedattn2_kernel<<<1152, 256, 0, stream>>>(x, wqkv, (float*)d_out);
}

// Round 7
// 112.748 us; speedup vs baseline: 1.1079x; 1.1079x over previous
//
#include <hip/hip_runtime.h>

// Problem constants
#define HW_   36864      // 192*192
#define WI    192
#define HT    192
#define CIN   128
#define DK    256        // == D_V
#define NH    8
#define DKH   32         // channels per head
// TEMPER = 16 -> scale 1/16 = 0.0625

using short4_ = __attribute__((ext_vector_type(4))) short;
using short8  = __attribute__((ext_vector_type(8))) short;
using float4_ = __attribute__((ext_vector_type(4))) float;

static __device__ __forceinline__ float b2f(unsigned short u) {
    union { unsigned int i; float f; } x; x.i = ((unsigned int)u) << 16; return x.f;
}
static __device__ __forceinline__ unsigned short f2b(float f) {
    union { float f; unsigned int i; } x; x.f = f;
    unsigned int r = x.i + 0x7FFFu + ((x.i >> 16) & 1u);   // round-nearest-even
    return (unsigned short)(r >> 16);
}

// ---------------------------------------------------------------------------
// Kernel 2: fused projection (r2-verified structure, -8.9us), with kernel 1
// FOLDED IN: the A-dbuf staging reads fp32 weights directly and converts
// inline (same f2b -> bit-identical LDS bytes as the old convw+wqkv path).
// Interleaved row layout per head (verified r1):
//   rows  0-15 : q[ 0:16]   rows 16-31 : k[ 0:16]   rows 32-47 : v[ 0:16]
//   rows 48-63 : q[16:32]   rows 64-79 : k[16:32]   rows 80-95 : v[16:32]
// 2x2 wave split, double-buffered A staging, one barrier per head.
// LDS = 53.2 KB -> 3 blocks/CU.
// ---------------------------------------------------------------------------
__device__ __forceinline__ void stageA(
    const float* __restrict__ wq, const float* __restrict__ wk,
    const float* __restrict__ wv, int head, int t,
    unsigned short* __restrict__ Ad)
{
    #pragma unroll
    for (int i = 0; i < 6; ++i) {
        int id = i * 256 + t;                  // 1536 8-float chunks
        int row = id >> 4, c8 = id & 15;
        int g = row >> 4;                      // 0..5
        int gm = g % 3;                        // 0=q 1=k 2=v
        int rr = ((g >= 3) ? 16 : 0) + (row & 15);
        const float* __restrict__ s = (gm == 0) ? wq : ((gm == 1) ? wk : wv);
        const float* __restrict__ sp = s + (head * 32 + rr) * 128 + c8 * 8;
        float4_ f0 = *(const float4_*)&sp[0];
        float4_ f1 = *(const float4_*)&sp[4];
        short8 v;
        #pragma unroll
        for (int j = 0; j < 4; ++j) {
            v[j]     = (short)f2b(f0[j]);
            v[4 + j] = (short)f2b(f1[j]);
        }
        *(short8*)&Ad[row * 136 + c8 * 8] = v;
    }
}

__global__ __launch_bounds__(256) void projfused3_kernel(
    const float* __restrict__ x,               // [128][HW] fp32
    const float* __restrict__ wq,              // [256][128] fp32
    const float* __restrict__ wk,
    const float* __restrict__ wv,
    unsigned short* __restrict__ vbuf,         // [8][HW][32] bf16
    float* __restrict__ sbuf)                  // [8][HW] fp32
{
    __shared__ unsigned short ShA[2][96 * 136];  // A double buffer (B-tile aliases ShA[0])
    __shared__ float sP[2][2][64];               // [parity][wm][px] q.k partials

    const int px0 = blockIdx.x * 64;
    const int t   = threadIdx.x;
    const int lane = t & 63, wave = t >> 6;
    const int col  = lane & 15, quad = lane >> 4;
    const int wm   = wave >> 1, wn = wave & 1;

    // ---- Stage B into ShA[0] low region: Bs[p][c] = bf16(x[c][px0+p]) ----
    unsigned short* Bs = &ShA[0][0];
    #pragma unroll 4
    for (int i = 0; i < 32; ++i) {
        int id = i * 256 + t;
        int c = id >> 6, p = id & 63;
        Bs[p * 136 + c] = f2b(x[c * HW_ + px0 + p]);
    }
    __syncthreads();

    // ---- B fragments into registers: lane holds pixel n = wn*32+nt*16+col ----
    short8 bfrag[2][4];
    #pragma unroll
    for (int nt = 0; nt < 2; ++nt) {
        int n = wn * 32 + nt * 16 + col;
        #pragma unroll
        for (int kt = 0; kt < 4; ++kt)
            bfrag[nt][kt] = *(const short8*)&Bs[n * 136 + kt * 32 + quad * 8];
    }
    __syncthreads();                           // B reads done; ShA[0] reusable

    // ---- Stage A head 0 into ShA[0] (inline fp32->bf16) ----
    stageA(wq, wk, wv, 0, t, &ShA[0][0]);
    __syncthreads();

    for (int head = 0; head < 8; ++head) {
        // ---- prefetch head+1 into the other buffer (overlaps compute) ----
        if (head < 7)
            stageA(wq, wk, wv, head + 1, t, &ShA[(head + 1) & 1][0]);
        const unsigned short* __restrict__ As = &ShA[head & 1][0];

        float4_ acc[3][2];
        #pragma unroll
        for (int mt = 0; mt < 3; ++mt) {
            acc[mt][0] = (float4_){0.f, 0.f, 0.f, 0.f};
            acc[mt][1] = (float4_){0.f, 0.f, 0.f, 0.f};
        }

        // mt: 0=q-chunk 1=k-chunk 2=v-chunk of this wm half
        #pragma unroll
        for (int mt = 0; mt < 3; ++mt) {
            #pragma unroll
            for (int kt = 0; kt < 4; ++kt) {
                short8 a = *(const short8*)&As[(wm * 48 + mt * 16 + col) * 136 + kt * 32 + quad * 8];
                acc[mt][0] = __builtin_amdgcn_mfma_f32_16x16x32_bf16(a, bfrag[0][kt], acc[mt][0], 0, 0, 0);
                acc[mt][1] = __builtin_amdgcn_mfma_f32_16x16x32_bf16(a, bfrag[1][kt], acc[mt][1], 0, 0, 0);
            }
        }

        // ---- Epilogue (r4-verified). C/D: col = pixel, row = quad*4+reg ----
        #pragma unroll
        for (int nt = 0; nt < 2; ++nt) {
            int px = px0 + wn * 32 + nt * 16 + col;
            float s = 0.f;
            #pragma unroll
            for (int reg = 0; reg < 4; ++reg)
                s += acc[0][nt][reg] * acc[1][nt][reg];   // q.k partial (16 dk of this wm)
            s += __shfl_xor(s, 16, 64);
            s += __shfl_xor(s, 32, 64);
            if (quad == 0) sP[head & 1][wm][wn * 32 + nt * 16 + col] = s;
            // v output channels dv = wm*16 + quad*4 + reg
            unsigned short* vp = vbuf + ((size_t)head * HW_ + px) * 32;
            short4_ v0;
            #pragma unroll
            for (int reg = 0; reg < 4; ++reg)
                v0[reg] = (short)f2b(acc[2][nt][reg]);
            *(short4_*)&vp[wm * 16 + quad * 4] = v0;
        }

        __syncthreads();   // (a) sP visible (b) prefetch h+1 landed (c) As reads done

        if (t < 64)
            sbuf[head * HW_ + px0 + t] = sP[head & 1][0][t] + sP[head & 1][1][t];
    }
}

// ---------------------------------------------------------------------------
// Kernel 3: regional softmax + weighted 3x3 gather, 16x8 tiles, LDS halo,
// XCD-head swizzle.  (r3-measured, UNCHANGED)
// ---------------------------------------------------------------------------
__global__ __launch_bounds__(256) void attn_kernel(
    const unsigned short* __restrict__ vbuf,  // [8][HW][32] bf16
    const float* __restrict__ sbuf,           // [8][HW]
    float* __restrict__ out)                  // [256][HW] fp32
{
    __shared__ unsigned short Vh[10][18][32]; // 11.25 KB halo V tile
    __shared__ float Ssc[10][18];             // 720 B halo scores
    __shared__ float tr[32][65];              // 8.3 KB transpose buffer

    const int b    = blockIdx.x;              // 2304 = 8 heads * 288 tiles
    const int wg   = (b & 7) * 288 + (b >> 3);   // XCD-head swizzle
    const int head = wg / 288;
    const int tile = wg - head * 288;
    const int t    = threadIdx.x;
    const int ty = tile / 12, tx = tile - ty * 12;   // 12 x 24 tile grid
    const int y0 = ty * 8, x0 = tx * 16;

    const unsigned short* __restrict__ vb = vbuf + (size_t)head * HW_ * 32;
    const float* __restrict__ Sg = sbuf + head * HW_;

    // ---- stage halo V: 180 cells x 64B = 720 16B chunks ----
    for (int id = t; id < 720; id += 256) {
        int cell = id >> 2, q = id & 3;
        int hy = cell / 18, hx = cell - hy * 18;
        int gy = y0 - 1 + hy; gy = gy < 0 ? 0 : (gy > HT - 1 ? HT - 1 : gy);
        int gx = x0 - 1 + hx; gx = gx < 0 ? 0 : (gx > WI - 1 ? WI - 1 : gx);
        *(short8*)&Vh[hy][hx][q * 8] =
            *(const short8*)&vb[((size_t)(gy * WI + gx)) * 32 + q * 8];
    }
    if (t < 180) {
        int hy = t / 18, hx = t - hy * 18;
        int gy = y0 - 1 + hy; gy = gy < 0 ? 0 : (gy > HT - 1 ? HT - 1 : gy);
        int gx = x0 - 1 + hx; gx = gx < 0 ? 0 : (gx > WI - 1 ? WI - 1 : gx);
        Ssc[hy][hx] = Sg[gy * WI + gx];
    }
    __syncthreads();

    // ---- per-pixel softmax over the 9 region slots (identical math) ----
    const int pxl = t >> 1;                   // 0..127
    const int hg  = t & 1;                    // 16-channel half
    const int ly  = pxl >> 4, lx = pxl & 15;  // 16 x 8 tile coords
    const int y   = y0 + ly, xx = x0 + lx;

    float w[9];
    float m = -1e30f;
    #pragma unroll
    for (int r = 0; r < 9; ++r) {
        int dy = r / 3 - 1, dx = r % 3 - 1;
        int ny = y + dy, nx = xx + dx;
        bool inb = (ny >= 0) && (ny < HT) && (nx >= 0) && (nx < WI);
        float val = inb ? (Ssc[ly + dy + 1][lx + dx + 1] * 0.0625f) : 0.0f;
        w[r] = val;
        m = fmaxf(m, val);
    }
    float wsum = 0.f;
    #pragma unroll
    for (int r = 0; r < 9; ++r) {
        float e = __expf(w[r] - m);
        w[r] = e;
        wsum += e;
    }
    float inv = 1.0f / wsum;
    #pragma unroll
    for (int r = 0; r < 9; ++r) {
        int dy = r / 3 - 1, dx = r % 3 - 1;
        int ny = y + dy, nx = xx + dx;
        bool inb = (ny >= 0) && (ny < HT) && (nx >= 0) && (nx < WI);
        w[r] = inb ? (w[r] * inv) : 0.0f;
    }

    // ---- weighted gather from LDS halo: 16 channels per thread ----
    float acc[16];
    #pragma unroll
    for (int j = 0; j < 16; ++j) acc[j] = 0.f;
    #pragma unroll
    for (int r = 0; r < 9; ++r) {
        int dy = r / 3 - 1, dx = r % 3 - 1;
        const unsigned short* vp = &Vh[ly + dy + 1][lx + dx + 1][hg * 16];
        short8 v8a = *(const short8*)&vp[0];
        short8 v8b = *(const short8*)&vp[8];
        #pragma unroll
        for (int j = 0; j < 8; ++j) {
            acc[j]     = fmaf(w[r], b2f((unsigned short)v8a[j]), acc[j]);
            acc[8 + j] = fmaf(w[r], b2f((unsigned short)v8b[j]), acc[8 + j]);
        }
    }

    // ---- write-out via tr[32][65], two 64-px halves (verified pattern) ----
    const int ch  = t >> 3;                   // 0..31
    const int sub = t & 7;
    const int ly2 = sub >> 1, xh = sub & 1;
    #pragma unroll
    for (int h = 0; h < 2; ++h) {
        if (h) __syncthreads();               // tr reuse protection
        if ((pxl >> 6) == h) {
            #pragma unroll
            for (int j = 0; j < 16; ++j)
                tr[hg * 16 + j][pxl & 63] = acc[j];
        }
        __syncthreads();
        float4_ o0, o1;
        #pragma unroll
        for (int j = 0; j < 4; ++j) {
            o0[j] = tr[ch][ly2 * 16 + xh * 8 + j];
            o1[j] = tr[ch][ly2 * 16 + xh * 8 + 4 + j];
        }
        float* o = out + (size_t)(head * DKH + ch) * HW_
                 + (y0 + h * 4 + ly2) * WI + x0 + xh * 8;
        *(float4_*)&o[0] = o0;
        *(float4_*)&o[4] = o1;
    }
}

// ---------------------------------------------------------------------------
// Workspace layout:
//   [0, 18874368)            vbuf : 8*36864*32 bf16 (pixel-major)
//   [18874368, 20054016)     sbuf : 8*36864 fp32
// ---------------------------------------------------------------------------
extern "C" void kernel_launch(void* const* d_in, const int* in_sizes, int n_in,
                              void* d_out, int out_size, void* d_ws, size_t ws_size,
                              hipStream_t stream) {
    const float* x  = (const float*)d_in[0];
    const float* wq = (const float*)d_in[1];
    const float* wk = (const float*)d_in[2];
    const float* wv = (const float*)d_in[3];

    char* ws = (char*)d_ws;
    unsigned short* vbuf = (unsigned short*)ws;
    float*          sbuf = (float*)(ws + 18874368);

    projfused3_kernel<<<576, 256, 0, stream>>>(x, wq, wk, wv, vbuf, sbuf);
    attn_kernel<<<2304, 256, 0, stream>>>(vbuf, sbuf, (float*)d_out);
}

// Round 8
// 109.429 us; speedup vs baseline: 1.1415x; 1.0303x over previous
//
#include <hip/hip_runtime.h>

// Problem constants
#define HW_   36864      // 192*192
#define WI    192
#define HT    192
#define CIN   128
#define DK    256        // == D_V
#define NH    8
#define DKH   32         // channels per head
// TEMPER = 16 -> scale 1/16 = 0.0625
// Inputs/output are fp32 (established rounds 2-7).

using short4_ = __attribute__((ext_vector_type(4))) short;
using short8  = __attribute__((ext_vector_type(8))) short;
using float4_ = __attribute__((ext_vector_type(4))) float;

static __device__ __forceinline__ float b2f(unsigned short u) {
    union { unsigned int i; float f; } x; x.i = ((unsigned int)u) << 16; return x.f;
}
static __device__ __forceinline__ unsigned short f2b(float f) {
    union { float f; unsigned int i; } x; x.f = f;
    unsigned int r = x.i + 0x7FFFu + ((x.i >> 16) & 1u);   // round-nearest-even
    return (unsigned short)(r >> 16);
}

// ---------------------------------------------------------------------------
// Kernel 1: weights fp32 -> bf16 wqkv[8][96][128], interleaved row layout
// per head (verified r1):
//   rows  0-15 : q[ 0:16]   rows 16-31 : k[ 0:16]   rows 32-47 : v[ 0:16]
//   rows 48-63 : q[16:32]   rows 64-79 : k[16:32]   rows 80-95 : v[16:32]
// Keeping this as a separate dispatch is MEASURED-better than folding the
// conversion into k2 (r7: +3.7us — fold doubles staging bytes to fp32 and
// puts f2b in the overlap-critical path).
// ---------------------------------------------------------------------------
__global__ __launch_bounds__(256) void convw_kernel(
    const float* __restrict__ wq,
    const float* __restrict__ wk,
    const float* __restrict__ wv,
    unsigned short* __restrict__ wqkv)
{
    int id = blockIdx.x * 256 + threadIdx.x;   // 98304 = 8*96*128
    int h   = id / 12288;
    int rem = id - h * 12288;
    int r   = rem >> 7;                        // 0..95
    int c   = rem & 127;
    int g   = r >> 4;                          // 0..5
    int gm  = g % 3;                           // 0=q 1=k 2=v
    int rr  = ((g >= 3) ? 16 : 0) + (r & 15);  // channel within head half
    const float* __restrict__ s = (gm == 0) ? wq : ((gm == 1) ? wk : wv);
    wqkv[id] = f2b(s[(h * 32 + rr) * 128 + c]);
}

// ---------------------------------------------------------------------------
// Kernel 2: fused projection, 2x2 wave split + double-buffered A staging
// (verified r2, -8.9us; best measured).  (r3 version, byte-identical)
// ---------------------------------------------------------------------------
__global__ __launch_bounds__(256) void projfused3_kernel(
    const float* __restrict__ x,               // [128][HW] fp32
    const unsigned short* __restrict__ wqkv,   // [8][96][128] bf16 (interleaved rows)
    unsigned short* __restrict__ vbuf,         // [8][HW][32] bf16
    float* __restrict__ sbuf)                  // [8][HW] fp32
{
    __shared__ unsigned short ShA[2][96 * 136];  // A double buffer (B-tile aliases ShA[0])
    __shared__ float sP[2][2][64];               // [parity][wm][px] q.k partials

    const int px0 = blockIdx.x * 64;
    const int t   = threadIdx.x;
    const int lane = t & 63, wave = t >> 6;
    const int col  = lane & 15, quad = lane >> 4;
    const int wm   = wave >> 1, wn = wave & 1;

    // ---- Stage B into ShA[0] low region: Bs[p][c] = bf16(x[c][px0+p]) ----
    unsigned short* Bs = &ShA[0][0];
    #pragma unroll 4
    for (int i = 0; i < 32; ++i) {
        int id = i * 256 + t;
        int c = id >> 6, p = id & 63;
        Bs[p * 136 + c] = f2b(x[c * HW_ + px0 + p]);
    }
    __syncthreads();

    // ---- B fragments into registers: lane holds pixel n = wn*32+nt*16+col ----
    short8 bfrag[2][4];
    #pragma unroll
    for (int nt = 0; nt < 2; ++nt) {
        int n = wn * 32 + nt * 16 + col;
        #pragma unroll
        for (int kt = 0; kt < 4; ++kt)
            bfrag[nt][kt] = *(const short8*)&Bs[n * 136 + kt * 32 + quad * 8];
    }
    __syncthreads();                           // B reads done; ShA[0] reusable

    // ---- Stage A head 0 into ShA[0] ----
    {
        const unsigned short* __restrict__ Ag = wqkv;
        #pragma unroll
        for (int i = 0; i < 6; ++i) {
            int id = i * 256 + t;              // 1536 16B chunks
            int row = id >> 4, c8 = id & 15;
            *(short8*)&ShA[0][row * 136 + c8 * 8] = *(const short8*)&Ag[row * 128 + c8 * 8];
        }
    }
    __syncthreads();

    for (int head = 0; head < 8; ++head) {
        // ---- prefetch head+1 into the other buffer (overlaps compute) ----
        if (head < 7) {
            const unsigned short* __restrict__ Ag = wqkv + (head + 1) * 96 * 128;
            unsigned short* __restrict__ Ad = &ShA[(head + 1) & 1][0];
            #pragma unroll
            for (int i = 0; i < 6; ++i) {
                int id = i * 256 + t;
                int row = id >> 4, c8 = id & 15;
                *(short8*)&Ad[row * 136 + c8 * 8] = *(const short8*)&Ag[row * 128 + c8 * 8];
            }
        }
        const unsigned short* __restrict__ As = &ShA[head & 1][0];

        float4_ acc[3][2];
        #pragma unroll
        for (int mt = 0; mt < 3; ++mt) {
            acc[mt][0] = (float4_){0.f, 0.f, 0.f, 0.f};
            acc[mt][1] = (float4_){0.f, 0.f, 0.f, 0.f};
        }

        // mt: 0=q-chunk 1=k-chunk 2=v-chunk of this wm half
        #pragma unroll
        for (int mt = 0; mt < 3; ++mt) {
            #pragma unroll
            for (int kt = 0; kt < 4; ++kt) {
                short8 a = *(const short8*)&As[(wm * 48 + mt * 16 + col) * 136 + kt * 32 + quad * 8];
                acc[mt][0] = __builtin_amdgcn_mfma_f32_16x16x32_bf16(a, bfrag[0][kt], acc[mt][0], 0, 0, 0);
                acc[mt][1] = __builtin_amdgcn_mfma_f32_16x16x32_bf16(a, bfrag[1][kt], acc[mt][1], 0, 0, 0);
            }
        }

        // ---- Epilogue. C/D: col = pixel, row(channel) = quad*4+reg ----
        #pragma unroll
        for (int nt = 0; nt < 2; ++nt) {
            int px = px0 + wn * 32 + nt * 16 + col;
            float s = 0.f;
            #pragma unroll
            for (int reg = 0; reg < 4; ++reg)
                s += acc[0][nt][reg] * acc[1][nt][reg];   // q.k partial (16 dk of this wm)
            s += __shfl_xor(s, 16, 64);
            s += __shfl_xor(s, 32, 64);
            if (quad == 0) sP[head & 1][wm][wn * 32 + nt * 16 + col] = s;
            // v output channels dv = wm*16 + quad*4 + reg
            unsigned short* vp = vbuf + ((size_t)head * HW_ + px) * 32;
            short4_ v0;
            #pragma unroll
            for (int reg = 0; reg < 4; ++reg)
                v0[reg] = (short)f2b(acc[2][nt][reg]);
            *(short4_*)&vp[wm * 16 + quad * 4] = v0;
        }

        __syncthreads();   // (a) sP visible (b) prefetch h+1 landed (c) As reads done

        if (t < 64)
            sbuf[head * HW_ + px0 + t] = sP[head & 1][0][t] + sP[head & 1][1][t];
    }
}

// ---------------------------------------------------------------------------
// Kernel 3: regional softmax + weighted 3x3 gather, 16x8 tiles, LDS halo,
// XCD-head swizzle.  (r3-measured, byte-identical)
// ---------------------------------------------------------------------------
__global__ __launch_bounds__(256) void attn_kernel(
    const unsigned short* __restrict__ vbuf,  // [8][HW][32] bf16
    const float* __restrict__ sbuf,           // [8][HW]
    float* __restrict__ out)                  // [256][HW] fp32
{
    __shared__ unsigned short Vh[10][18][32]; // 11.25 KB halo V tile
    __shared__ float Ssc[10][18];             // 720 B halo scores
    __shared__ float tr[32][65];              // 8.3 KB transpose buffer

    const int b    = blockIdx.x;              // 2304 = 8 heads * 288 tiles
    const int wg   = (b & 7) * 288 + (b >> 3);   // XCD-head swizzle
    const int head = wg / 288;
    const int tile = wg - head * 288;
    const int t    = threadIdx.x;
    const int ty = tile / 12, tx = tile - ty * 12;   // 12 x 24 tile grid
    const int y0 = ty * 8, x0 = tx * 16;

    const unsigned short* __restrict__ vb = vbuf + (size_t)head * HW_ * 32;
    const float* __restrict__ Sg = sbuf + head * HW_;

    // ---- stage halo V: 180 cells x 64B = 720 16B chunks ----
    for (int id = t; id < 720; id += 256) {
        int cell = id >> 2, q = id & 3;
        int hy = cell / 18, hx = cell - hy * 18;
        int gy = y0 - 1 + hy; gy = gy < 0 ? 0 : (gy > HT - 1 ? HT - 1 : gy);
        int gx = x0 - 1 + hx; gx = gx < 0 ? 0 : (gx > WI - 1 ? WI - 1 : gx);
        *(short8*)&Vh[hy][hx][q * 8] =
            *(const short8*)&vb[((size_t)(gy * WI + gx)) * 32 + q * 8];
    }
    if (t < 180) {
        int hy = t / 18, hx = t - hy * 18;
        int gy = y0 - 1 + hy; gy = gy < 0 ? 0 : (gy > HT - 1 ? HT - 1 : gy);
        int gx = x0 - 1 + hx; gx = gx < 0 ? 0 : (gx > WI - 1 ? WI - 1 : gx);
        Ssc[hy][hx] = Sg[gy * WI + gx];
    }
    __syncthreads();

    // ---- per-pixel softmax over the 9 region slots (identical math) ----
    const int pxl = t >> 1;                   // 0..127
    const int hg  = t & 1;                    // 16-channel half
    const int ly  = pxl >> 4, lx = pxl & 15;  // 16 x 8 tile coords
    const int y   = y0 + ly, xx = x0 + lx;

    float w[9];
    float m = -1e30f;
    #pragma unroll
    for (int r = 0; r < 9; ++r) {
        int dy = r / 3 - 1, dx = r % 3 - 1;
        int ny = y + dy, nx = xx + dx;
        bool inb = (ny >= 0) && (ny < HT) && (nx >= 0) && (nx < WI);
        float val = inb ? (Ssc[ly + dy + 1][lx + dx + 1] * 0.0625f) : 0.0f;
        w[r] = val;
        m = fmaxf(m, val);
    }
    float wsum = 0.f;
    #pragma unroll
    for (int r = 0; r < 9; ++r) {
        float e = __expf(w[r] - m);
        w[r] = e;
        wsum += e;
    }
    float inv = 1.0f / wsum;
    #pragma unroll
    for (int r = 0; r < 9; ++r) {
        int dy = r / 3 - 1, dx = r % 3 - 1;
        int ny = y + dy, nx = xx + dx;
        bool inb = (ny >= 0) && (ny < HT) && (nx >= 0) && (nx < WI);
        w[r] = inb ? (w[r] * inv) : 0.0f;
    }

    // ---- weighted gather from LDS halo: 16 channels per thread ----
    float acc[16];
    #pragma unroll
    for (int j = 0; j < 16; ++j) acc[j] = 0.f;
    #pragma unroll
    for (int r = 0; r < 9; ++r) {
        int dy = r / 3 - 1, dx = r % 3 - 1;
        const unsigned short* vp = &Vh[ly + dy + 1][lx + dx + 1][hg * 16];
        short8 v8a = *(const short8*)&vp[0];
        short8 v8b = *(const short8*)&vp[8];
        #pragma unroll
        for (int j = 0; j < 8; ++j) {
            acc[j]     = fmaf(w[r], b2f((unsigned short)v8a[j]), acc[j]);
            acc[8 + j] = fmaf(w[r], b2f((unsigned short)v8b[j]), acc[8 + j]);
        }
    }

    // ---- write-out via tr[32][65], two 64-px halves (verified pattern) ----
    const int ch  = t >> 3;                   // 0..31
    const int sub = t & 7;
    const int ly2 = sub >> 1, xh = sub & 1;
    #pragma unroll
    for (int h = 0; h < 2; ++h) {
        if (h) __syncthreads();               // tr reuse protection
        if ((pxl >> 6) == h) {
            #pragma unroll
            for (int j = 0; j < 16; ++j)
                tr[hg * 16 + j][pxl & 63] = acc[j];
        }
        __syncthreads();
        float4_ o0, o1;
        #pragma unroll
        for (int j = 0; j < 4; ++j) {
            o0[j] = tr[ch][ly2 * 16 + xh * 8 + j];
            o1[j] = tr[ch][ly2 * 16 + xh * 8 + 4 + j];
        }
        float* o = out + (size_t)(head * DKH + ch) * HW_
                 + (y0 + h * 4 + ly2) * WI + x0 + xh * 8;
        *(float4_*)&o[0] = o0;
        *(float4_*)&o[4] = o1;
    }
}

// ---------------------------------------------------------------------------
// Workspace layout:
//   [0, 196608)              wqkv : 8*96*128 bf16
//   [196608, 19071104)       vbuf : 8*36864*32 bf16 (pixel-major)
//   [19071104, 20250752)     sbuf : 8*36864 fp32
// ---------------------------------------------------------------------------
extern "C" void kernel_launch(void* const* d_in, const int* in_sizes, int n_in,
                              void* d_out, int out_size, void* d_ws, size_t ws_size,
                              hipStream_t stream) {
    const float* x  = (const float*)d_in[0];
    const float* wq = (const float*)d_in[1];
    const float* wk = (const float*)d_in[2];
    const float* wv = (const float*)d_in[3];

    char* ws = (char*)d_ws;
    unsigned short* wqkv = (unsigned short*)ws;
    unsigned short* vbuf = (unsigned short*)(ws + 196608);
    float*          sbuf = (float*)(ws + 19071104);

    convw_kernel<<<384, 256, 0, stream>>>(wq, wk, wv, wqkv);
    projfused3_kernel<<<576, 256, 0, stream>>>(x, wqkv, vbuf, sbuf);
    attn_kernel<<<2304, 256, 0, stream>>>(vbuf, sbuf, (float*)d_out);
}